// Round 4
// baseline (327.962 us; speedup 1.0000x reference)
//
#include <hip/hip_runtime.h>

#define LN_EPS 1e-5f
#define D 128
#define SCAN_CHUNK 1024
#define LDSA_STRIDE 264   // bf16 units: 256 + 8 pad; row stride 528B (16B-aligned)

typedef __attribute__((ext_vector_type(4))) float f32x4;
typedef __attribute__((ext_vector_type(8))) short bf16x8;

static __device__ __forceinline__ ushort f2bf(float f) {
    union { float f; unsigned u; } a; a.f = f;
    unsigned r = a.u + 0x7FFF + ((a.u >> 16) & 1);   // RNE
    return (ushort)(r >> 16);
}
static __device__ __forceinline__ float bf2f(ushort u) {
    union { unsigned u; float f; } a; a.u = ((unsigned)u) << 16;
    return a.f;
}

// K0: pack B = [Wl^T ; Wr^T] (256k x 128j) into MFMA B-fragment order:
// lane L of frag (ks,jb) holds B[k = ks*32 + (L>>4)*8 + i][j = jb*16 + (L&15)].
__global__ void prep_w(const float* __restrict__ Wl,
                       const float* __restrict__ Wr,
                       ushort* __restrict__ Bfrag) {
    int t = blockIdx.x * blockDim.x + threadIdx.x;   // 32768 entries
    if (t >= 8 * 8 * 64 * 8) return;
    int i    = t & 7;
    int lane = (t >> 3) & 63;
    int jb   = (t >> 9) & 7;
    int ks   = t >> 12;
    int k = ks * 32 + (lane >> 4) * 8 + i;
    int j = jb * 16 + (lane & 15);
    float v = (k < D) ? Wl[j * D + k] : Wr[j * D + (k - D)];
    Bfrag[t] = f2bf(v);
}

// K1: LayerNorm + ReLU + dropout-mask -> bf16 h. One 64-lane wave per node.
__global__ void ln_relu_drop(const float* __restrict__ x,
                             const float* __restrict__ mask,
                             const float* __restrict__ gamma,
                             const float* __restrict__ beta,
                             ushort* __restrict__ hbf, int N) {
    int node = (blockIdx.x * blockDim.x + threadIdx.x) >> 6;
    int lane = threadIdx.x & 63;
    if (node >= N) return;
    float2 v = ((const float2*)(x + (size_t)node * D))[lane];
    float s  = v.x + v.y;
    float ss = v.x * v.x + v.y * v.y;
#pragma unroll
    for (int off = 32; off > 0; off >>= 1) {
        s  += __shfl_xor(s, off);
        ss += __shfl_xor(ss, off);
    }
    float mu  = s * (1.0f / D);
    float var = ss * (1.0f / D) - mu * mu;
    float rs  = rsqrtf(var + LN_EPS);
    float2 g = ((const float2*)gamma)[lane];
    float2 b = ((const float2*)beta)[lane];
    float2 m = ((const float2*)(mask + (size_t)node * D))[lane];
    ushort2 o;
    o.x = f2bf(fmaxf((v.x - mu) * rs * g.x + b.x, 0.0f) * m.x);
    o.y = f2bf(fmaxf((v.y - mu) * rs * g.y + b.y, 0.0f) * m.y);
    ((ushort2*)(hbf + (size_t)node * D))[lane] = o;
}

// K2: degree histogram over dst (int atomics).
__global__ void hist_k(const int* __restrict__ ei, int* __restrict__ hist, int E) {
    int e = blockIdx.x * blockDim.x + threadIdx.x;
    if (e >= E) return;
    atomicAdd(&hist[ei[E + e]], 1);
}

// K3a: per-chunk exclusive scan (1024 elems / block of 256 threads).
__global__ void scan1(const int* __restrict__ hist, int* __restrict__ offs,
                      int* __restrict__ chunk_sums, int N) {
    __shared__ int lds[256];
    int base = blockIdx.x * SCAN_CHUNK;
    int t = threadIdx.x;
    int idx0 = base + t * 4;
    int v[4];
#pragma unroll
    for (int i = 0; i < 4; i++) {
        int idx = idx0 + i;
        v[i] = (idx < N) ? hist[idx] : 0;
    }
    lds[t] = v[0] + v[1] + v[2] + v[3];
    __syncthreads();
    for (int off = 1; off < 256; off <<= 1) {
        int add = (t >= off) ? lds[t - off] : 0;
        __syncthreads();
        lds[t] += add;
        __syncthreads();
    }
    int run = (t == 0) ? 0 : lds[t - 1];
    if (t == 255) chunk_sums[blockIdx.x] = lds[255];
#pragma unroll
    for (int i = 0; i < 4; i++) {
        int idx = idx0 + i;
        if (idx < N) offs[idx] = run;
        run += v[i];
    }
}

// K3b: single-block exclusive scan of the chunk sums (C <= 128).
__global__ void scan2(int* __restrict__ chunk_sums, int C) {
    __shared__ int lds[128];
    int t = threadIdx.x;
    lds[t] = (t < C) ? chunk_sums[t] : 0;
    __syncthreads();
    for (int off = 1; off < 128; off <<= 1) {
        int add = (t >= off) ? lds[t - off] : 0;
        __syncthreads();
        lds[t] += add;
        __syncthreads();
    }
    int excl = (t == 0) ? 0 : lds[t - 1];
    if (t < C) chunk_sums[t] = excl;
}

// K3c: add chunk bases; also init the scatter cursor.
__global__ void scan3(int* __restrict__ offs, const int* __restrict__ chunk_sums,
                      int* __restrict__ cursor, int N) {
    int i = blockIdx.x * blockDim.x + threadIdx.x;
    if (i >= N) return;
    int v = offs[i] + chunk_sums[i / SCAN_CHUNK];
    offs[i] = v;
    cursor[i] = v;
}

// K4: bucket edges by dst (counting-sort placement; int atomics only).
__global__ void sort_edges(const int* __restrict__ ei, int* __restrict__ cursor,
                           int* __restrict__ sorted_src, int E) {
    int e = blockIdx.x * blockDim.x + threadIdx.x;
    if (e >= E) return;
    int dst = ei[E + e];
    int pos = atomicAdd(&cursor[dst], 1);
    sorted_src[pos] = ei[e];
}

// K5: fused mean-aggregate + dual GEMM.
// Block = 256 threads = 4 waves; tile = 64 nodes x 128 j.
// Phase 0: load B frags to VGPRs (latency covered by phase 1).
// Phase 1: cooperative copy of the tile's own h rows into A[k=128..255];
//          per-wave edge gathers (bf16 rows, L3-resident) accumulate the
//          mean-agg into A[k=0..127].
// Phase 2: 64x MFMA 16x16x32 bf16 + bias epilogue -> fp32 out.
__global__ void __launch_bounds__(256, 3)
agg_gemm(float* __restrict__ out,
         const ushort* __restrict__ hbf,
         const int* __restrict__ sorted_src,
         const int* __restrict__ offs,
         const int* __restrict__ hist,
         const ushort* __restrict__ Bfrag,
         const float* __restrict__ bl,
         int N) {
    __shared__ ushort Alds[64 * LDSA_STRIDE];
    int tid  = threadIdx.x;
    int wave = tid >> 6;
    int lane = tid & 63;
    int n0 = blockIdx.x * 64;

    // Phase 0: B fragments for this wave's 2 j-blocks (16 dwordx4 loads).
    bf16x8 breg[8][2];
#pragma unroll
    for (int ks = 0; ks < 8; ks++)
#pragma unroll
        for (int jj = 0; jj < 2; jj++) {
            int jb = wave * 2 + jj;
            breg[ks][jj] = *(const bf16x8*)(Bfrag + (size_t)((ks * 8 + jb) * 64 + lane) * 8);
        }

    // Phase 1a: cooperative copy of h rows into A upper half (k=128..255).
#pragma unroll
    for (int it = 0; it < 4; it++) {
        int chunk = tid + 256 * it;          // 0..1023: 64 rows x 16 chunks
        int row = chunk >> 4;
        int c8  = chunk & 15;
        int node = n0 + row;
        bf16x8 v = (bf16x8){0, 0, 0, 0, 0, 0, 0, 0};
        if (node < N) v = *(const bf16x8*)(hbf + (size_t)node * D + c8 * 8);
        *(bf16x8*)&Alds[row * LDSA_STRIDE + 128 + c8 * 8] = v;
    }

    // Phase 1b: per-wave mean-agg gathers into A lower half (k=0..127).
    for (int i = 0; i < 16; i++) {
        int row = wave * 16 + i;
        int node = n0 + row;
        float ax = 0.0f, ay = 0.0f;
        int deg = 0;
        if (node < N) {
            int start = offs[node];
            deg = hist[node];
            for (int base = 0; base < deg; base += 64) {
                int m = deg - base; if (m > 64) m = 64;
                int srci = (lane < m) ? sorted_src[start + base + lane] : 0;
                for (int t = 0; t < m; t++) {
                    int src = __shfl(srci, t);
                    ushort2 hv = ((const ushort2*)(hbf + (size_t)src * D))[lane];
                    ax += bf2f(hv.x); ay += bf2f(hv.y);
                }
            }
        }
        float inv = 1.0f / fmaxf((float)deg, 1.0f);
        ushort2 o; o.x = f2bf(ax * inv); o.y = f2bf(ay * inv);
        *(ushort2*)&Alds[row * LDSA_STRIDE + lane * 2] = o;
    }
    __syncthreads();

    // Phase 2: MFMA.
    f32x4 acc[4][2];
#pragma unroll
    for (int nb = 0; nb < 4; nb++)
#pragma unroll
        for (int jj = 0; jj < 2; jj++)
            acc[nb][jj] = (f32x4){0.f, 0.f, 0.f, 0.f};

    int arow = lane & 15;
    int akoff = (lane >> 4) * 8;
#pragma unroll
    for (int ks = 0; ks < 8; ks++) {
#pragma unroll
        for (int nb = 0; nb < 4; nb++) {
            bf16x8 a = *(const bf16x8*)&Alds[(nb * 16 + arow) * LDSA_STRIDE + ks * 32 + akoff];
            acc[nb][0] = __builtin_amdgcn_mfma_f32_16x16x32_bf16(a, breg[ks][0], acc[nb][0], 0, 0, 0);
            acc[nb][1] = __builtin_amdgcn_mfma_f32_16x16x32_bf16(a, breg[ks][1], acc[nb][1], 0, 0, 0);
        }
    }

    // Epilogue: C[row = nb*16 + (lane>>4)*4 + r][col = wave*32 + jj*16 + (lane&15)]
    float bias0 = bl[wave * 32 + (lane & 15)];
    float bias1 = bl[wave * 32 + 16 + (lane & 15)];
    int rbase = (lane >> 4) * 4;
#pragma unroll
    for (int nb = 0; nb < 4; nb++) {
#pragma unroll
        for (int r = 0; r < 4; r++) {
            int row = nb * 16 + rbase + r;
            if (n0 + row < N) {
                float* orow = out + (size_t)(n0 + row) * D + wave * 32 + (lane & 15);
                orow[0]  = acc[nb][0][r] + bias0;
                orow[16] = acc[nb][1][r] + bias1;
            }
        }
    }
}

extern "C" void kernel_launch(void* const* d_in, const int* in_sizes, int n_in,
                              void* d_out, int out_size, void* d_ws, size_t ws_size,
                              hipStream_t stream) {
    const float* x     = (const float*)d_in[0];
    const int*   ei    = (const int*)  d_in[1];
    const float* mask  = (const float*)d_in[2];
    const float* gamma = (const float*)d_in[3];
    const float* beta  = (const float*)d_in[4];
    const float* Wl    = (const float*)d_in[5];
    const float* bl    = (const float*)d_in[6];
    const float* Wr    = (const float*)d_in[7];
    float* out = (float*)d_out;

    int N = in_sizes[0] / D;   // 100000
    int E = in_sizes[1] / 2;   // 600000
    int chunks = (N + SCAN_CHUNK - 1) / SCAN_CHUNK;  // 98

    // ws layout: hbf[N*D] ushort | Bfrag[32768] ushort | hist[N] | offs[N]
    //            | cursor[N] | chunk_sums[128] | sorted_src[E]
    ushort* hbf   = (ushort*)d_ws;
    ushort* Bfrag = hbf + (size_t)N * D;
    int* hist   = (int*)(Bfrag + 32768);
    int* offs   = hist + N;
    int* cursor = offs + N;
    int* csums  = cursor + N;
    int* ssrc   = csums + 128;

    hipMemsetAsync(hist, 0, (size_t)N * sizeof(int), stream);
    prep_w<<<128, 256, 0, stream>>>(Wl, Wr, Bfrag);
    ln_relu_drop<<<(N + 3) / 4, 256, 0, stream>>>(x, mask, gamma, beta, hbf, N);
    hist_k<<<(E + 255) / 256, 256, 0, stream>>>(ei, hist, E);
    scan1<<<chunks, 256, 0, stream>>>(hist, offs, csums, N);
    scan2<<<1, 128, 0, stream>>>(csums, chunks);
    scan3<<<(N + 255) / 256, 256, 0, stream>>>(offs, csums, cursor, N);
    sort_edges<<<(E + 255) / 256, 256, 0, stream>>>(ei, cursor, ssrc, E);
    agg_gemm<<<(N + 63) / 64, 256, 0, stream>>>(out, hbf, ssrc, offs, hist, Bfrag, bl, N);
}

// Round 5
// 273.664 us; speedup vs baseline: 1.1984x; 1.1984x over previous
//
#include <hip/hip_runtime.h>

#define LN_EPS 1e-5f
#define D 128
#define SCAN_CHUNK 1024
#define LDSA_STRIDE 264   // bf16 units: 256 + 8 pad; row stride 528B (16B-aligned)

typedef __attribute__((ext_vector_type(4))) float f32x4;
typedef __attribute__((ext_vector_type(8))) short bf16x8;

static __device__ __forceinline__ ushort f2bf(float f) {
    union { float f; unsigned u; } a; a.f = f;
    unsigned r = a.u + 0x7FFF + ((a.u >> 16) & 1);   // RNE
    return (ushort)(r >> 16);
}
static __device__ __forceinline__ float bf2f(ushort u) {
    union { unsigned u; float f; } a; a.u = ((unsigned)u) << 16;
    return a.f;
}

// K0: pack B = [Wl^T ; Wr^T] (256k x 128j) into MFMA B-fragment order:
// lane L of frag (ks,jb) holds B[k = ks*32 + (L>>4)*8 + i][j = jb*16 + (L&15)].
__global__ void prep_w(const float* __restrict__ Wl,
                       const float* __restrict__ Wr,
                       ushort* __restrict__ Bfrag) {
    int t = blockIdx.x * blockDim.x + threadIdx.x;   // 32768 entries
    if (t >= 8 * 8 * 64 * 8) return;
    int i    = t & 7;
    int lane = (t >> 3) & 63;
    int jb   = (t >> 9) & 7;
    int ks   = t >> 12;
    int k = ks * 32 + (lane >> 4) * 8 + i;
    int j = jb * 16 + (lane & 15);
    float v = (k < D) ? Wl[j * D + k] : Wr[j * D + (k - D)];
    Bfrag[t] = f2bf(v);
}

// K1: LayerNorm + ReLU + dropout-mask -> bf16 h. One 64-lane wave per node.
__global__ void ln_relu_drop(const float* __restrict__ x,
                             const float* __restrict__ mask,
                             const float* __restrict__ gamma,
                             const float* __restrict__ beta,
                             ushort* __restrict__ hbf, int N) {
    int node = (blockIdx.x * blockDim.x + threadIdx.x) >> 6;
    int lane = threadIdx.x & 63;
    if (node >= N) return;
    float2 v = ((const float2*)(x + (size_t)node * D))[lane];
    float s  = v.x + v.y;
    float ss = v.x * v.x + v.y * v.y;
#pragma unroll
    for (int off = 32; off > 0; off >>= 1) {
        s  += __shfl_xor(s, off);
        ss += __shfl_xor(ss, off);
    }
    float mu  = s * (1.0f / D);
    float var = ss * (1.0f / D) - mu * mu;
    float rs  = rsqrtf(var + LN_EPS);
    float2 g = ((const float2*)gamma)[lane];
    float2 b = ((const float2*)beta)[lane];
    float2 m = ((const float2*)(mask + (size_t)node * D))[lane];
    ushort2 o;
    o.x = f2bf(fmaxf((v.x - mu) * rs * g.x + b.x, 0.0f) * m.x);
    o.y = f2bf(fmaxf((v.y - mu) * rs * g.y + b.y, 0.0f) * m.y);
    ((ushort2*)(hbf + (size_t)node * D))[lane] = o;
}

// K2: degree histogram over dst (int atomics).
__global__ void hist_k(const int* __restrict__ ei, int* __restrict__ hist, int E) {
    int e = blockIdx.x * blockDim.x + threadIdx.x;
    if (e >= E) return;
    atomicAdd(&hist[ei[E + e]], 1);
}

// K3a: per-chunk exclusive scan (1024 elems / block of 256 threads).
__global__ void scan1(const int* __restrict__ hist, int* __restrict__ offs,
                      int* __restrict__ chunk_sums, int N) {
    __shared__ int lds[256];
    int base = blockIdx.x * SCAN_CHUNK;
    int t = threadIdx.x;
    int idx0 = base + t * 4;
    int v[4];
#pragma unroll
    for (int i = 0; i < 4; i++) {
        int idx = idx0 + i;
        v[i] = (idx < N) ? hist[idx] : 0;
    }
    lds[t] = v[0] + v[1] + v[2] + v[3];
    __syncthreads();
    for (int off = 1; off < 256; off <<= 1) {
        int add = (t >= off) ? lds[t - off] : 0;
        __syncthreads();
        lds[t] += add;
        __syncthreads();
    }
    int run = (t == 0) ? 0 : lds[t - 1];
    if (t == 255) chunk_sums[blockIdx.x] = lds[255];
#pragma unroll
    for (int i = 0; i < 4; i++) {
        int idx = idx0 + i;
        if (idx < N) offs[idx] = run;
        run += v[i];
    }
}

// K3b: single-block exclusive scan of the chunk sums (C <= 128).
__global__ void scan2(int* __restrict__ chunk_sums, int C) {
    __shared__ int lds[128];
    int t = threadIdx.x;
    lds[t] = (t < C) ? chunk_sums[t] : 0;
    __syncthreads();
    for (int off = 1; off < 128; off <<= 1) {
        int add = (t >= off) ? lds[t - off] : 0;
        __syncthreads();
        lds[t] += add;
        __syncthreads();
    }
    int excl = (t == 0) ? 0 : lds[t - 1];
    if (t < C) chunk_sums[t] = excl;
}

// K3c: add chunk bases; also init the scatter cursor.
__global__ void scan3(int* __restrict__ offs, const int* __restrict__ chunk_sums,
                      int* __restrict__ cursor, int N) {
    int i = blockIdx.x * blockDim.x + threadIdx.x;
    if (i >= N) return;
    int v = offs[i] + chunk_sums[i / SCAN_CHUNK];
    offs[i] = v;
    cursor[i] = v;
}

// K4: bucket edges by dst (counting-sort placement; int atomics only).
__global__ void sort_edges(const int* __restrict__ ei, int* __restrict__ cursor,
                           int* __restrict__ sorted_src, int E) {
    int e = blockIdx.x * blockDim.x + threadIdx.x;
    if (e >= E) return;
    int dst = ei[E + e];
    int pos = atomicAdd(&cursor[dst], 1);
    sorted_src[pos] = ei[e];
}

// K5: segmented mean-aggregate, 4 nodes per wave (16 lanes x bf16x8 = one
// 256B row read per node per iteration -> 4 independent gather chains/wave).
__global__ void aggregate4(const ushort* __restrict__ hbf,
                           const int* __restrict__ sorted_src,
                           const int* __restrict__ offs,
                           const int* __restrict__ hist,
                           ushort* __restrict__ magg, int N) {
    int wid  = (blockIdx.x * blockDim.x + threadIdx.x) >> 6;
    int lane = threadIdx.x & 63;
    int g  = lane >> 4;        // subgroup 0..3 -> node
    int sl = lane & 15;        // 16 lanes x 8 bf16 = 128 elems
    int node = wid * 4 + g;
    bool valid = node < N;
    int start = 0, deg = 0;
    if (valid) { start = offs[node]; deg = hist[node]; }
    float acc[8];
#pragma unroll
    for (int j = 0; j < 8; j++) acc[j] = 0.0f;
    for (int i = 0; ; i++) {
        bool act = (i < deg);
        if (!__any(act)) break;
        if (act) {
            int src = sorted_src[start + i];
            bf16x8 v = *(const bf16x8*)(hbf + (size_t)src * D + sl * 8);
#pragma unroll
            for (int j = 0; j < 8; j++) acc[j] += bf2f((ushort)v[j]);
        }
    }
    if (valid) {
        float inv = 1.0f / fmaxf((float)deg, 1.0f);
        bf16x8 o;
#pragma unroll
        for (int j = 0; j < 8; j++) o[j] = (short)f2bf(acc[j] * inv);
        *(bf16x8*)(magg + (size_t)node * D + sl * 8) = o;
    }
}

// K6: out = [magg | h] @ B + bias via bf16 MFMA.
// Block = 256 threads = 4 waves; tile = 64 nodes x 128 j. A staged by pure
// bf16 copies (no conversion); B fragments pre-packed, kept in VGPRs.
__global__ void __launch_bounds__(256, 3)
out_gemm_mfma(float* __restrict__ out,
              const ushort* __restrict__ magg,
              const ushort* __restrict__ hbf,
              const ushort* __restrict__ Bfrag,
              const float* __restrict__ bl,
              int N) {
    __shared__ ushort Alds[64 * LDSA_STRIDE];
    int tid  = threadIdx.x;
    int wave = tid >> 6;
    int lane = tid & 63;
    int n0 = blockIdx.x * 64;

    // B fragments for this wave's 2 j-blocks (16 dwordx4 loads).
    bf16x8 breg[8][2];
#pragma unroll
    for (int ks = 0; ks < 8; ks++)
#pragma unroll
        for (int jj = 0; jj < 2; jj++) {
            int jb = wave * 2 + jj;
            breg[ks][jj] = *(const bf16x8*)(Bfrag + (size_t)((ks * 8 + jb) * 64 + lane) * 8);
        }

    // Stage A: k=0..127 from magg, k=128..255 from hbf (16B per thread-chunk).
#pragma unroll
    for (int it = 0; it < 4; it++) {
        int chunk = tid + 256 * it;          // 0..1023: 64 rows x 16 chunks
        int row = chunk >> 4;
        int c8  = chunk & 15;
        int node = n0 + row;
        bf16x8 va = (bf16x8){0,0,0,0,0,0,0,0};
        bf16x8 vh = (bf16x8){0,0,0,0,0,0,0,0};
        if (node < N) {
            va = *(const bf16x8*)(magg + (size_t)node * D + c8 * 8);
            vh = *(const bf16x8*)(hbf  + (size_t)node * D + c8 * 8);
        }
        *(bf16x8*)&Alds[row * LDSA_STRIDE + c8 * 8]       = va;
        *(bf16x8*)&Alds[row * LDSA_STRIDE + 128 + c8 * 8] = vh;
    }
    __syncthreads();

    f32x4 acc[4][2];
#pragma unroll
    for (int nb = 0; nb < 4; nb++)
#pragma unroll
        for (int jj = 0; jj < 2; jj++)
            acc[nb][jj] = (f32x4){0.f, 0.f, 0.f, 0.f};

    int arow = lane & 15;
    int akoff = (lane >> 4) * 8;
#pragma unroll
    for (int ks = 0; ks < 8; ks++) {
#pragma unroll
        for (int nb = 0; nb < 4; nb++) {
            bf16x8 a = *(const bf16x8*)&Alds[(nb * 16 + arow) * LDSA_STRIDE + ks * 32 + akoff];
            acc[nb][0] = __builtin_amdgcn_mfma_f32_16x16x32_bf16(a, breg[ks][0], acc[nb][0], 0, 0, 0);
            acc[nb][1] = __builtin_amdgcn_mfma_f32_16x16x32_bf16(a, breg[ks][1], acc[nb][1], 0, 0, 0);
        }
    }

    // Epilogue: C[row = nb*16 + (lane>>4)*4 + r][col = wave*32 + jj*16 + (lane&15)]
    float bias0 = bl[wave * 32 + (lane & 15)];
    float bias1 = bl[wave * 32 + 16 + (lane & 15)];
    int rbase = (lane >> 4) * 4;
#pragma unroll
    for (int nb = 0; nb < 4; nb++) {
#pragma unroll
        for (int r = 0; r < 4; r++) {
            int row = nb * 16 + rbase + r;
            if (n0 + row < N) {
                float* orow = out + (size_t)(n0 + row) * D + wave * 32 + (lane & 15);
                orow[0]  = acc[nb][0][r] + bias0;
                orow[16] = acc[nb][1][r] + bias1;
            }
        }
    }
}

extern "C" void kernel_launch(void* const* d_in, const int* in_sizes, int n_in,
                              void* d_out, int out_size, void* d_ws, size_t ws_size,
                              hipStream_t stream) {
    const float* x     = (const float*)d_in[0];
    const int*   ei    = (const int*)  d_in[1];
    const float* mask  = (const float*)d_in[2];
    const float* gamma = (const float*)d_in[3];
    const float* beta  = (const float*)d_in[4];
    const float* Wl    = (const float*)d_in[5];
    const float* bl    = (const float*)d_in[6];
    const float* Wr    = (const float*)d_in[7];
    float* out = (float*)d_out;

    int N = in_sizes[0] / D;   // 100000
    int E = in_sizes[1] / 2;   // 600000
    int chunks = (N + SCAN_CHUNK - 1) / SCAN_CHUNK;  // 98

    // ws layout: hbf[N*D] us | magg[N*D] us | Bfrag[32768] us | hist[N]
    //            | offs[N] | cursor[N] | chunk_sums[128] | sorted_src[E]
    ushort* hbf   = (ushort*)d_ws;
    ushort* magg  = hbf + (size_t)N * D;
    ushort* Bfrag = magg + (size_t)N * D;
    int* hist   = (int*)(Bfrag + 32768);
    int* offs   = hist + N;
    int* cursor = offs + N;
    int* csums  = cursor + N;
    int* ssrc   = csums + 128;

    hipMemsetAsync(hist, 0, (size_t)N * sizeof(int), stream);
    prep_w<<<128, 256, 0, stream>>>(Wl, Wr, Bfrag);
    ln_relu_drop<<<(N + 3) / 4, 256, 0, stream>>>(x, mask, gamma, beta, hbf, N);
    hist_k<<<(E + 255) / 256, 256, 0, stream>>>(ei, hist, E);
    scan1<<<chunks, 256, 0, stream>>>(hist, offs, csums, N);
    scan2<<<1, 128, 0, stream>>>(csums, chunks);
    scan3<<<(N + 255) / 256, 256, 0, stream>>>(offs, csums, cursor, N);
    sort_edges<<<(E + 255) / 256, 256, 0, stream>>>(ei, cursor, ssrc, E);
    aggregate4<<<((N + 3) / 4 + 3) / 4, 256, 0, stream>>>(hbf, ssrc, offs, hist, magg, N);
    out_gemm_mfma<<<(N + 63) / 64, 256, 0, stream>>>(out, magg, hbf, Bfrag, bl, N);
}

// Round 6
// 264.950 us; speedup vs baseline: 1.2378x; 1.0329x over previous
//
#include <hip/hip_runtime.h>

#define LN_EPS 1e-5f
#define D 128
#define SCAN_CHUNK 1024
#define LDSA_STRIDE 264   // bf16 units: 256 + 8 pad; row stride 528B (16B-aligned)

typedef __attribute__((ext_vector_type(4))) float f32x4;
typedef __attribute__((ext_vector_type(8))) short bf16x8;

static __device__ __forceinline__ ushort f2bf(float f) {
    union { float f; unsigned u; } a; a.f = f;
    unsigned r = a.u + 0x7FFF + ((a.u >> 16) & 1);   // RNE
    return (ushort)(r >> 16);
}
static __device__ __forceinline__ float bf2f(ushort u) {
    union { unsigned u; float f; } a; a.u = ((unsigned)u) << 16;
    return a.f;
}

// K0: pack B = [Wl^T ; Wr^T] (256k x 128j) into MFMA B-fragment order:
// lane L of frag (ks,jb) holds B[k = ks*32 + (L>>4)*8 + i][j = jb*16 + (L&15)].
__global__ void prep_w(const float* __restrict__ Wl,
                       const float* __restrict__ Wr,
                       ushort* __restrict__ Bfrag) {
    int t = blockIdx.x * blockDim.x + threadIdx.x;   // 32768 entries
    if (t >= 8 * 8 * 64 * 8) return;
    int i    = t & 7;
    int lane = (t >> 3) & 63;
    int jb   = (t >> 9) & 7;
    int ks   = t >> 12;
    int k = ks * 32 + (lane >> 4) * 8 + i;
    int j = jb * 16 + (lane & 15);
    float v = (k < D) ? Wl[j * D + k] : Wr[j * D + (k - D)];
    Bfrag[t] = f2bf(v);
}

// K1 (merged): blocks [0, lnBlocks) do LayerNorm+ReLU+mask -> bf16 h
// (one 64-lane wave per node); blocks [lnBlocks, ...) do the dst-degree
// histogram (one thread per edge). Disjoint inputs, per-block uniform branch.
__global__ void ln_hist(const float* __restrict__ x,
                        const float* __restrict__ mask,
                        const float* __restrict__ gamma,
                        const float* __restrict__ beta,
                        ushort* __restrict__ hbf,
                        const int* __restrict__ ei,
                        int* __restrict__ hist,
                        int N, int E, int lnBlocks) {
    if (blockIdx.x >= (unsigned)lnBlocks) {
        int e = (blockIdx.x - lnBlocks) * blockDim.x + threadIdx.x;
        if (e < E) atomicAdd(&hist[ei[E + e]], 1);
        return;
    }
    int node = (blockIdx.x * blockDim.x + threadIdx.x) >> 6;
    int lane = threadIdx.x & 63;
    if (node >= N) return;
    float2 v = ((const float2*)(x + (size_t)node * D))[lane];
    float s  = v.x + v.y;
    float ss = v.x * v.x + v.y * v.y;
#pragma unroll
    for (int off = 32; off > 0; off >>= 1) {
        s  += __shfl_xor(s, off);
        ss += __shfl_xor(ss, off);
    }
    float mu  = s * (1.0f / D);
    float var = ss * (1.0f / D) - mu * mu;
    float rs  = rsqrtf(var + LN_EPS);
    float2 g = ((const float2*)gamma)[lane];
    float2 b = ((const float2*)beta)[lane];
    float2 m = ((const float2*)(mask + (size_t)node * D))[lane];
    ushort2 o;
    o.x = f2bf(fmaxf((v.x - mu) * rs * g.x + b.x, 0.0f) * m.x);
    o.y = f2bf(fmaxf((v.y - mu) * rs * g.y + b.y, 0.0f) * m.y);
    ((ushort2*)(hbf + (size_t)node * D))[lane] = o;
}

// K2a: per-chunk exclusive scan (1024 elems / block); csums[b] = chunk total.
__global__ void scan1(const int* __restrict__ hist, int* __restrict__ offs,
                      int* __restrict__ chunk_sums, int N) {
    __shared__ int lds[256];
    int base = blockIdx.x * SCAN_CHUNK;
    int t = threadIdx.x;
    int idx0 = base + t * 4;
    int v[4];
#pragma unroll
    for (int i = 0; i < 4; i++) {
        int idx = idx0 + i;
        v[i] = (idx < N) ? hist[idx] : 0;
    }
    lds[t] = v[0] + v[1] + v[2] + v[3];
    __syncthreads();
    for (int off = 1; off < 256; off <<= 1) {
        int add = (t >= off) ? lds[t - off] : 0;
        __syncthreads();
        lds[t] += add;
        __syncthreads();
    }
    int run = (t == 0) ? 0 : lds[t - 1];
    if (t == 255) chunk_sums[blockIdx.x] = lds[255];
#pragma unroll
    for (int i = 0; i < 4; i++) {
        int idx = idx0 + i;
        if (idx < N) offs[idx] = run;
        run += v[i];
    }
}

// K2b: add chunk base (computed in-block from raw chunk totals; <=98 of them)
// and init the scatter cursor. 256 elems per block -> chunk uniform per block.
__global__ void scan_fix(int* __restrict__ offs, const int* __restrict__ csums,
                         int* __restrict__ cursor, int N) {
    __shared__ int base_s;
    int chunk = (blockIdx.x * 256) / SCAN_CHUNK;
    int t = threadIdx.x;
    if (t < 64) {
        int v = 0;
        for (int c = t; c < chunk; c += 64) v += csums[c];
#pragma unroll
        for (int off = 32; off > 0; off >>= 1) v += __shfl_xor(v, off);
        if (t == 0) base_s = v;
    }
    __syncthreads();
    int i = blockIdx.x * 256 + t;
    if (i >= N) return;
    int v = offs[i] + base_s;
    offs[i] = v;
    cursor[i] = v;
}

// K3: bucket edges by dst (counting-sort placement; int atomics only).
__global__ void sort_edges(const int* __restrict__ ei, int* __restrict__ cursor,
                           int* __restrict__ sorted_src, int E) {
    int e = blockIdx.x * blockDim.x + threadIdx.x;
    if (e >= E) return;
    int dst = ei[E + e];
    int pos = atomicAdd(&cursor[dst], 1);
    sorted_src[pos] = ei[e];
}

// K4: segmented mean-aggregate, 4 nodes per wave (16 lanes x bf16x8 = one
// 256B row read per node). Edge loop unrolled x2 -> two independent
// row-gathers in flight per chain; 8-VGPR kernel keeps full occupancy.
__global__ void aggregate4(const ushort* __restrict__ hbf,
                           const int* __restrict__ sorted_src,
                           const int* __restrict__ offs,
                           const int* __restrict__ hist,
                           ushort* __restrict__ magg, int N) {
    int wid  = (blockIdx.x * blockDim.x + threadIdx.x) >> 6;
    int lane = threadIdx.x & 63;
    int g  = lane >> 4;        // subgroup 0..3 -> node
    int sl = lane & 15;        // 16 lanes x 8 bf16 = 128 elems
    int node = wid * 4 + g;
    bool valid = node < N;
    int start = 0, deg = 0;
    if (valid) { start = offs[node]; deg = hist[node]; }
    float acc[8];
#pragma unroll
    for (int j = 0; j < 8; j++) acc[j] = 0.0f;
    int i = 0;
    for (; i + 2 <= deg; i += 2) {
        int s0 = sorted_src[start + i];
        int s1 = sorted_src[start + i + 1];
        bf16x8 v0 = *(const bf16x8*)(hbf + (size_t)s0 * D + sl * 8);
        bf16x8 v1 = *(const bf16x8*)(hbf + (size_t)s1 * D + sl * 8);
#pragma unroll
        for (int j = 0; j < 8; j++)
            acc[j] += bf2f((ushort)v0[j]) + bf2f((ushort)v1[j]);
    }
    if (i < deg) {
        int s0 = sorted_src[start + i];
        bf16x8 v0 = *(const bf16x8*)(hbf + (size_t)s0 * D + sl * 8);
#pragma unroll
        for (int j = 0; j < 8; j++) acc[j] += bf2f((ushort)v0[j]);
    }
    if (valid) {
        float inv = 1.0f / fmaxf((float)deg, 1.0f);
        bf16x8 o;
#pragma unroll
        for (int j = 0; j < 8; j++) o[j] = (short)f2bf(acc[j] * inv);
        *(bf16x8*)(magg + (size_t)node * D + sl * 8) = o;
    }
}

// K5: out = [magg | h] @ B + bias via bf16 MFMA.
// Block = 256 threads = 4 waves; tile = 64 nodes x 128 j. A staged by pure
// bf16 copies; B fragments pre-packed, kept in VGPRs.
__global__ void __launch_bounds__(256, 3)
out_gemm_mfma(float* __restrict__ out,
              const ushort* __restrict__ magg,
              const ushort* __restrict__ hbf,
              const ushort* __restrict__ Bfrag,
              const float* __restrict__ bl,
              int N) {
    __shared__ ushort Alds[64 * LDSA_STRIDE];
    int tid  = threadIdx.x;
    int wave = tid >> 6;
    int lane = tid & 63;
    int n0 = blockIdx.x * 64;

    bf16x8 breg[8][2];
#pragma unroll
    for (int ks = 0; ks < 8; ks++)
#pragma unroll
        for (int jj = 0; jj < 2; jj++) {
            int jb = wave * 2 + jj;
            breg[ks][jj] = *(const bf16x8*)(Bfrag + (size_t)((ks * 8 + jb) * 64 + lane) * 8);
        }

#pragma unroll
    for (int it = 0; it < 4; it++) {
        int chunk = tid + 256 * it;          // 0..1023: 64 rows x 16 chunks
        int row = chunk >> 4;
        int c8  = chunk & 15;
        int node = n0 + row;
        bf16x8 va = (bf16x8){0,0,0,0,0,0,0,0};
        bf16x8 vh = (bf16x8){0,0,0,0,0,0,0,0};
        if (node < N) {
            va = *(const bf16x8*)(magg + (size_t)node * D + c8 * 8);
            vh = *(const bf16x8*)(hbf  + (size_t)node * D + c8 * 8);
        }
        *(bf16x8*)&Alds[row * LDSA_STRIDE + c8 * 8]       = va;
        *(bf16x8*)&Alds[row * LDSA_STRIDE + 128 + c8 * 8] = vh;
    }
    __syncthreads();

    f32x4 acc[4][2];
#pragma unroll
    for (int nb = 0; nb < 4; nb++)
#pragma unroll
        for (int jj = 0; jj < 2; jj++)
            acc[nb][jj] = (f32x4){0.f, 0.f, 0.f, 0.f};

    int arow = lane & 15;
    int akoff = (lane >> 4) * 8;
#pragma unroll
    for (int ks = 0; ks < 8; ks++) {
#pragma unroll
        for (int nb = 0; nb < 4; nb++) {
            bf16x8 a = *(const bf16x8*)&Alds[(nb * 16 + arow) * LDSA_STRIDE + ks * 32 + akoff];
            acc[nb][0] = __builtin_amdgcn_mfma_f32_16x16x32_bf16(a, breg[ks][0], acc[nb][0], 0, 0, 0);
            acc[nb][1] = __builtin_amdgcn_mfma_f32_16x16x32_bf16(a, breg[ks][1], acc[nb][1], 0, 0, 0);
        }
    }

    float bias0 = bl[wave * 32 + (lane & 15)];
    float bias1 = bl[wave * 32 + 16 + (lane & 15)];
    int rbase = (lane >> 4) * 4;
#pragma unroll
    for (int nb = 0; nb < 4; nb++) {
#pragma unroll
        for (int r = 0; r < 4; r++) {
            int row = nb * 16 + rbase + r;
            if (n0 + row < N) {
                float* orow = out + (size_t)(n0 + row) * D + wave * 32 + (lane & 15);
                orow[0]  = acc[nb][0][r] + bias0;
                orow[16] = acc[nb][1][r] + bias1;
            }
        }
    }
}

extern "C" void kernel_launch(void* const* d_in, const int* in_sizes, int n_in,
                              void* d_out, int out_size, void* d_ws, size_t ws_size,
                              hipStream_t stream) {
    const float* x     = (const float*)d_in[0];
    const int*   ei    = (const int*)  d_in[1];
    const float* mask  = (const float*)d_in[2];
    const float* gamma = (const float*)d_in[3];
    const float* beta  = (const float*)d_in[4];
    const float* Wl    = (const float*)d_in[5];
    const float* bl    = (const float*)d_in[6];
    const float* Wr    = (const float*)d_in[7];
    float* out = (float*)d_out;

    int N = in_sizes[0] / D;   // 100000
    int E = in_sizes[1] / 2;   // 600000
    int chunks = (N + SCAN_CHUNK - 1) / SCAN_CHUNK;  // 98

    // ws layout: hbf[N*D] us | magg[N*D] us | Bfrag[32768] us | hist[N]
    //            | offs[N] | cursor[N] | chunk_sums[128] | sorted_src[E]
    ushort* hbf   = (ushort*)d_ws;
    ushort* magg  = hbf + (size_t)N * D;
    ushort* Bfrag = magg + (size_t)N * D;
    int* hist   = (int*)(Bfrag + 32768);
    int* offs   = hist + N;
    int* cursor = offs + N;
    int* csums  = cursor + N;
    int* ssrc   = csums + 128;

    int lnBlocks = (N + 3) / 4;
    int histBlocks = (E + 255) / 256;

    hipMemsetAsync(hist, 0, (size_t)N * sizeof(int), stream);
    prep_w<<<128, 256, 0, stream>>>(Wl, Wr, Bfrag);
    ln_hist<<<lnBlocks + histBlocks, 256, 0, stream>>>(x, mask, gamma, beta, hbf,
                                                       ei, hist, N, E, lnBlocks);
    scan1<<<chunks, 256, 0, stream>>>(hist, offs, csums, N);
    scan_fix<<<(N + 255) / 256, 256, 0, stream>>>(offs, csums, cursor, N);
    sort_edges<<<(E + 255) / 256, 256, 0, stream>>>(ei, cursor, ssrc, E);
    aggregate4<<<((N + 3) / 4 + 3) / 4, 256, 0, stream>>>(hbf, ssrc, offs, hist, magg, N);
    out_gemm_mfma<<<(N + 63) / 64, 256, 0, stream>>>(out, magg, hbf, Bfrag, bl, N);
}